// Round 6
// baseline (254.925 us; speedup 1.0000x reference)
//
#include <hip/hip_runtime.h>

// Problem constants
constexpr int Bc  = 4;
constexpr int Sc  = 384;
constexpr int Dc  = 300;
constexpr int Ec  = 50;
constexpr int HDc = 150;          // D / L
constexpr int WHC = 350;          // Wh row length
constexpr int MT  = Bc * Sc;      // 1536

typedef __attribute__((ext_vector_type(8))) short bf16x8;
typedef __attribute__((ext_vector_type(4))) float f32x4;

__device__ __forceinline__ short f2bf(float x) {
    union { float f; unsigned u; } v; v.f = x;
    unsigned r = (v.u + 0x7FFFu + ((v.u >> 16) & 1u)) >> 16;
    return (short)r;
}

__device__ __forceinline__ float bf2f(short s) {
    union { unsigned u; float f; } v; v.u = ((unsigned)(unsigned short)s) << 16;
    return v.f;
}

// ---------------------------------------------------------------------------
// bf16 MFMA GEMM body (round-2-verified form) — used only by fused1's gemm3.
// ---------------------------------------------------------------------------
template<int BSRC, int A1M, int HASD, int HASB, int RELU, int PRE>
__device__ __forceinline__ void mgemm_body(
    short* As, short* Bs, int bx, int by, int b,
    const float* __restrict__ A, int lda, long sA,
    const float* __restrict__ Bw, int ldb, long sB,
    const float* __restrict__ W1a, const float* __restrict__ WoutP,
    const float* __restrict__ Dm, int ldd, long sD,
    const float* __restrict__ bias, float bscale,
    const float* __restrict__ s12, const float* __restrict__ sm,
    float* __restrict__ C, int ldc, long sC,
    int M, int N, int K)
{
    const float* Ap = A + (long)b * sA;
    const float* Bp = Bw + (long)b * sB;
    const float* Dp = Dm + (long)b * sD;
    float* Cp = C + (long)b * sC;

    const int tid  = threadIdx.x;
    const int wave = tid >> 6, lane = tid & 63;
    const int wm = wave & 1, wn = wave >> 1;
    const int lm = lane & 15, quad = lane >> 4;
    const int m0 = by * 32, n0 = bx * 32;

    const int srow = tid >> 3;
    const int sk   = (tid & 7) * 8;
    const int nc   = tid & 31;
    const int kr   = tid >> 5;

    float sbh = 0.f; const float* s1p = nullptr; float s2v = 0.f;
    if constexpr (A1M) {
        sbh = sm[384];
        s1p = s12 + 2L * Sc * b;
        s2v = s1p[2 * (m0 + srow) + 1];
    }

    const int cn = n0 + wn * 16 + lm;
    float bpre = 0.f;
    float dpre[4] = {0.f, 0.f, 0.f, 0.f};
    if constexpr (PRE) {
        if constexpr (HASB) { if (cn < N) bpre = bias[cn]; }
        if constexpr (HASD) {
            #pragma unroll
            for (int r = 0; r < 4; ++r) {
                int cm = m0 + wm * 16 + quad * 4 + r;
                if (cn < N && cm < M) dpre[r] = Dp[(long)cm * ldd + cn];
            }
        }
    }

    float ra[8], rb[8];

    auto stageA = [&](int k0) {
        int am = m0 + srow;
        int kb = k0 + sk;
        if constexpr (A1M) {
            float4 u = *(const float4*)(Ap + (long)am * lda + kb);
            float4 w = *(const float4*)(Ap + (long)am * lda + kb + 4);
            const float* up = (const float*)&u;
            const float* wp = (const float*)&w;
            #pragma unroll
            for (int j = 0; j < 4; ++j) {
                ra[j]     = (up[j] + s1p[2*(kb + j)]     + s2v + sbh) * (1.0f/Ec);
                ra[4 + j] = (wp[j] + s1p[2*(kb + 4 + j)] + s2v + sbh) * (1.0f/Ec);
            }
        } else {
            if (kb + 7 < K) {
                float4 u = *(const float4*)(Ap + (long)am * lda + kb);
                float4 w = *(const float4*)(Ap + (long)am * lda + kb + 4);
                ra[0]=u.x; ra[1]=u.y; ra[2]=u.z; ra[3]=u.w;
                ra[4]=w.x; ra[5]=w.y; ra[6]=w.z; ra[7]=w.w;
            } else {
                #pragma unroll
                for (int j = 0; j < 8; ++j) {
                    int k = kb + j;
                    ra[j] = (k < K) ? Ap[(long)am * lda + k] : 0.f;
                }
            }
        }
    };

    auto stageB = [&](int k0) {
        if constexpr (BSRC == 0) {
            int n = n0 + nc;
            bool nok = n < N;
            #pragma unroll
            for (int p = 0; p < 8; ++p) {
                int k = k0 + kr + p * 8;
                rb[p] = nok ? Bp[(long)k * ldb + n] : 0.f;
            }
        } else {
            int nr = n0 + srow;
            bool nok = nr < N;
            const float* wp = Bp; int ld = ldb; int nn = nr;
            if constexpr (BSRC == 2) {
                if (nr < 150)      { wp = Bp;    ld = 300; nn = nr; }
                else if (nr < 300) { wp = W1a;   ld = 450; nn = nr - 150; }
                else               { wp = WoutP; ld = 300; nn = nr - 300; }
            }
            #pragma unroll
            for (int p = 0; p < 4; ++p) {
                int k = k0 + sk + 2 * p;
                if (nok && k + 1 < K) {
                    float2 v = *(const float2*)(wp + (long)nn * ld + k);
                    rb[2*p] = v.x; rb[2*p + 1] = v.y;
                } else {
                    rb[2*p]     = (nok && k < K)     ? wp[(long)nn * ld + k]     : 0.f;
                    rb[2*p + 1] = (nok && k + 1 < K) ? wp[(long)nn * ld + k + 1] : 0.f;
                }
            }
        }
    };

    auto stash = [&]() {
        #pragma unroll
        for (int j = 0; j < 8; ++j) As[srow * 72 + sk + j] = f2bf(ra[j]);
        if constexpr (BSRC == 0) {
            #pragma unroll
            for (int p = 0; p < 8; ++p) Bs[nc * 72 + kr + p * 8] = f2bf(rb[p]);
        } else {
            #pragma unroll
            for (int j = 0; j < 8; ++j) Bs[srow * 72 + sk + j] = f2bf(rb[j]);
        }
    };

    f32x4 acc = {0.f, 0.f, 0.f, 0.f};

    stageA(0); stageB(0);
    for (int k0 = 0; k0 < K; k0 += 64) {
        __syncthreads();
        stash();
        __syncthreads();
        if (k0 + 64 < K) { stageA(k0 + 64); stageB(k0 + 64); }
        {
            bf16x8 a0 = *(const bf16x8*)(As + (wm*16 + lm) * 72 + quad * 8);
            bf16x8 b0 = *(const bf16x8*)(Bs + (wn*16 + lm) * 72 + quad * 8);
            acc = __builtin_amdgcn_mfma_f32_16x16x32_bf16(a0, b0, acc, 0, 0, 0);
            bf16x8 a1 = *(const bf16x8*)(As + (wm*16 + lm) * 72 + 32 + quad * 8);
            bf16x8 b1 = *(const bf16x8*)(Bs + (wn*16 + lm) * 72 + 32 + quad * 8);
            acc = __builtin_amdgcn_mfma_f32_16x16x32_bf16(a1, b1, acc, 0, 0, 0);
        }
    }

    if (cn < N) {
        #pragma unroll
        for (int r = 0; r < 4; ++r) {
            int cm = m0 + wm * 16 + quad * 4 + r;
            if (cm < M) {
                float v = acc[r];
                if constexpr (HASD) v += PRE ? dpre[r] : Dp[(long)cm * ldd + cn];
                if constexpr (HASB) v += bscale * (PRE ? bpre : bias[cn]);
                if constexpr (RELU) v = fmaxf(v, 0.f);
                Cp[(long)cm * ldc + cn] = v;
            }
        }
    }
}

// ---------------------------------------------------------------------------
// D1: gemm3 (912 blocks) + sm prep (1 block) + adj reduction (9216 blocks).
// Byte-identical to the r5-verified version.
// ---------------------------------------------------------------------------
__global__ __launch_bounds__(256)
void fused1(const float* __restrict__ adj, const float* __restrict__ X,
            const float* __restrict__ W0, const float* __restrict__ W1,
            const float* __restrict__ Wout, const float* __restrict__ Wh,
            const float* __restrict__ bh,
            float* __restrict__ sm, float* __restrict__ A0,
            float* __restrict__ wadj, float* __restrict__ R)
{
    __shared__ float lds[64 * 51 + 64];      // 13312 B union
    const int bx = blockIdx.x, t = threadIdx.x;

    if (bx < 912) {
        short* As = (short*)lds;
        short* Bs = As + 32 * 72;
        mgemm_body<2,0,0,0,0,0>(As, Bs, bx % 19, bx / 19, 0,
            X, Dc, 0, W0, 300, 0, W1, Wout,
            nullptr, 0, 0, nullptr, 0.f, nullptr, nullptr,
            R, 600, 0, MT, 600, Dc);
    } else if (bx == 912) {
        for (int u = t; u < 512; u += 256) {
            if (u < Ec) {
                float s = 0.f;
                for (int e = 0; e < Ec; ++e) s += Wh[e*WHC + u];
                sm[u] = s;
            } else if (u >= 64 && u < 64 + HDc) {
                int h = u - 64; float s = 0.f;
                for (int e = 0; e < Ec; ++e) s += Wh[e*WHC + Ec + h];
                sm[u] = s;
            } else if (u >= 224 && u < 224 + HDc) {
                int h = u - 224; float s = 0.f;
                for (int e = 0; e < Ec; ++e) s += Wh[e*WHC + Ec + HDc + h];
                sm[u] = s;
            } else if (u == 384) {
                float s = 0.f;
                for (int e = 0; e < Ec; ++e) s += bh[e];
                sm[u] = s;
            }
        }
    } else {
        const int unit = bx - 913;
        float* tile = lds;
        float* wec  = lds + 64 * 51;

        long base = (long)unit * 3200;
        const float4* p4 = (const float4*)(adj + base);
        float4 v0 = p4[t];
        float4 v1 = p4[t + 256];
        float4 v2 = p4[t + 512];
        float4 v3 = {0.f, 0.f, 0.f, 0.f};
        if (t < 32) v3 = p4[t + 768];

        if (t < Ec) {
            float s = 0.f;
            for (int e = 0; e < Ec; ++e) s += Wh[e * WHC + t];
            wec[t] = s;
        }

        auto scat = [&](int i, const float4& v) {
            const float* vp = (const float*)&v;
            #pragma unroll
            for (int j = 0; j < 4; ++j) {
                int e = 4 * i + j;
                tile[(e / 50) * 51 + (e % 50)] = vp[j];
            }
        };
        scat(t, v0);
        scat(t + 256, v1);
        scat(t + 512, v2);
        if (t < 32) scat(t + 768, v3);
        __syncthreads();

        int r = t >> 2, q = t & 3;
        int h0 = q * 13, h1 = (q == 3) ? 50 : h0 + 13;
        const float* row = tile + r * 51;
        float s = 0.f, w = 0.f;
        for (int i = h0; i < h1; ++i) { float v = row[i]; s += v; w += v * wec[i]; }
        s += __shfl_xor(s, 1); w += __shfl_xor(w, 1);
        s += __shfl_xor(s, 2); w += __shfl_xor(w, 2);
        if (q == 0) {
            int g = unit * 64 + r;
            A0[g]   = s * (1.0f / Ec);
            wadj[g] = w;
        }
    }
}

// ---------------------------------------------------------------------------
// fused23: one block per 32-row strip (48 blocks = 12 m-tiles x 4 batches).
// Phase A: G0 strip = relu(A0@P0 + P0 + 2 b0), K=384, all 5 N-tiles per
//          K-step (B staged for 150 cols at once) -> G0 kept in LDS only.
// Then:    s12 (f32 VALU dot from LDS) ; P1 = Q1 + G0@W1b^T (write R) ;
//          out = G0@WoutL^T + R3 + bout.
// G0 never touches global. LDS: A6 27.6K + Bs5 23K + Gs 13.8K = 63 KB.
// ---------------------------------------------------------------------------
__global__ __launch_bounds__(256)
void fused23(const float* __restrict__ A0, float* __restrict__ R,
             const float* __restrict__ W1, const float* __restrict__ Wout,
             const float* __restrict__ b0v, const float* __restrict__ boutv,
             const float* __restrict__ smv, float* __restrict__ s12,
             float* __restrict__ out)
{
    __shared__ short A6[6 * 2304];
    __shared__ short Bs5[5 * 2304];
    __shared__ short Gs[3 * 2304];

    const int tid  = threadIdx.x;
    const int wave = tid >> 6, lane = tid & 63;
    const int wm = wave & 1, wn = wave >> 1;
    const int lm = lane & 15, quad = lane >> 4;
    const int srow = tid >> 3, sk = (tid & 7) * 8;
    const int nc = tid & 31, kr = tid >> 5;
    const int cml = wm * 16 + quad * 4;          // local C-row base (+r)

    const int b  = blockIdx.x / 12;
    const int m0 = (blockIdx.x % 12) * 32;
    const int gm0 = b * Sc + m0;                 // flat row base
    const float* Ap = A0 + (long)b * (Sc * Sc);
    const float* Pp = R  + (long)b * (Sc * 600);

    for (int i = tid; i < 3 * 2304; i += 256) Gs[i] = 0;

    // A strip (32x384 f32) -> A6 bf16
    #pragma unroll
    for (int c = 0; c < 6; ++c) {
        const float* ap = Ap + (long)(m0 + srow) * Sc + c * 64 + sk;
        float4 u = *(const float4*)ap;
        float4 w = *(const float4*)(ap + 4);
        short* d = A6 + c * 2304 + srow * 72 + sk;
        d[0]=f2bf(u.x); d[1]=f2bf(u.y); d[2]=f2bf(u.z); d[3]=f2bf(u.w);
        d[4]=f2bf(w.x); d[5]=f2bf(w.y); d[6]=f2bf(w.z); d[7]=f2bf(w.w);
    }

    // phase-A epilogue preloads (P0 strip + b0)
    float dpre[5][4], b0pre[5];
    #pragma unroll
    for (int nt = 0; nt < 5; ++nt) {
        int cn = nt * 32 + wn * 16 + lm;
        b0pre[nt] = (cn < 150) ? b0v[cn] : 0.f;
        #pragma unroll
        for (int r = 0; r < 4; ++r)
            dpre[nt][r] = (cn < 150) ? Pp[(long)(m0 + cml + r) * 600 + cn] : 0.f;
    }

    float rbs[5][8];
    f32x4 acc[5];
    const f32x4 fz = {0.f, 0.f, 0.f, 0.f};

    auto stageB_P = [&](int k0) {                // P0 k-major, 5 tiles
        #pragma unroll
        for (int nt = 0; nt < 5; ++nt) {
            int n = nt * 32 + nc; bool nok = n < 150;
            #pragma unroll
            for (int p = 0; p < 8; ++p)
                rbs[nt][p] = nok ? Pp[(long)(k0 + kr + p * 8) * 600 + n] : 0.f;
        }
    };
    auto stashB_k = [&]() {
        #pragma unroll
        for (int nt = 0; nt < 5; ++nt)
            #pragma unroll
            for (int p = 0; p < 8; ++p)
                Bs5[nt * 2304 + nc * 72 + kr + p * 8] = f2bf(rbs[nt][p]);
    };
    auto stageB_W = [&](const float* Wbase, int ldw, int nbase, int nlim,
                        int klim, int k0) {      // row-major weights, 5 tiles
        #pragma unroll
        for (int nt = 0; nt < 5; ++nt) {
            int nr = nbase + nt * 32 + srow; bool nok = nr < nlim;
            const float* wp = Wbase + (long)nr * ldw;
            #pragma unroll
            for (int p = 0; p < 4; ++p) {
                int k = k0 + sk + 2 * p;
                rbs[nt][2*p]   = (nok && k     < klim) ? wp[k]     : 0.f;
                rbs[nt][2*p+1] = (nok && k + 1 < klim) ? wp[k + 1] : 0.f;
            }
        }
    };
    auto stashB_r = [&]() {
        #pragma unroll
        for (int nt = 0; nt < 5; ++nt)
            #pragma unroll
            for (int j = 0; j < 8; ++j)
                Bs5[nt * 2304 + srow * 72 + sk + j] = f2bf(rbs[nt][j]);
    };
    auto mfma5 = [&](const short* Abase, int ki) {
        const short* Af = Abase + ki * 2304 + (wm * 16 + lm) * 72;
        bf16x8 a0 = *(const bf16x8*)(Af + quad * 8);
        bf16x8 a1 = *(const bf16x8*)(Af + 32 + quad * 8);
        #pragma unroll
        for (int nt = 0; nt < 5; ++nt) {
            const short* Bf = Bs5 + nt * 2304 + (wn * 16 + lm) * 72;
            acc[nt] = __builtin_amdgcn_mfma_f32_16x16x32_bf16(
                a0, *(const bf16x8*)(Bf + quad * 8), acc[nt], 0, 0, 0);
            acc[nt] = __builtin_amdgcn_mfma_f32_16x16x32_bf16(
                a1, *(const bf16x8*)(Bf + 32 + quad * 8), acc[nt], 0, 0, 0);
        }
    };

    // ---- Phase A: G0 strip ------------------------------------------------
    #pragma unroll
    for (int nt = 0; nt < 5; ++nt) acc[nt] = fz;
    stageB_P(0);
    for (int ki = 0; ki < 6; ++ki) {
        __syncthreads();
        stashB_k();
        __syncthreads();
        if (ki < 5) stageB_P((ki + 1) * 64);
        mfma5(A6, ki);
    }
    #pragma unroll
    for (int nt = 0; nt < 5; ++nt) {
        int cn = nt * 32 + wn * 16 + lm;
        if (cn < 150) {
            #pragma unroll
            for (int r = 0; r < 4; ++r) {
                float g = fmaxf(acc[nt][r] + dpre[nt][r] + 2.f * b0pre[nt], 0.f);
                Gs[(cn >> 6) * 2304 + (cml + r) * 72 + (cn & 63)] = f2bf(g);
            }
        }
    }
    __syncthreads();

    // Q1 preload for phase C (hides under s12 pass)
    float dq[5][4];
    #pragma unroll
    for (int nt = 0; nt < 5; ++nt) {
        int cn = nt * 32 + wn * 16 + lm;
        #pragma unroll
        for (int r = 0; r < 4; ++r)
            dq[nt][r] = (cn < 150) ? Pp[(long)(m0 + cml + r) * 600 + 150 + cn] : 0.f;
    }

    // ---- s12 from Gs (f32 accumulate) -------------------------------------
    {
        int row = tid >> 3, p = tid & 7;
        int c0 = p * 19, c1 = (c0 + 19 < 150) ? c0 + 19 : 150;
        float a = 0.f, c2 = 0.f;
        for (int c = c0; c < c1; ++c) {
            float g = bf2f(Gs[(c >> 6) * 2304 + row * 72 + (c & 63)]);
            a  += g * smv[64 + c];
            c2 += g * smv[224 + c];
        }
        a += __shfl_xor(a, 1);  c2 += __shfl_xor(c2, 1);
        a += __shfl_xor(a, 2);  c2 += __shfl_xor(c2, 2);
        a += __shfl_xor(a, 4);  c2 += __shfl_xor(c2, 4);
        if (p == 0) { s12[2 * (gm0 + row)] = a; s12[2 * (gm0 + row) + 1] = c2; }
    }

    // ---- Phase C: P1 = Q1 + G0 @ W1b^T  (N=150, K=150 via zero-padded Gs) -
    #pragma unroll
    for (int nt = 0; nt < 5; ++nt) acc[nt] = fz;
    stageB_W(W1 + Dc, 450, 0, 150, 150, 0);
    for (int ki = 0; ki < 3; ++ki) {
        __syncthreads();
        stashB_r();
        __syncthreads();
        if (ki < 2) stageB_W(W1 + Dc, 450, 0, 150, 150, (ki + 1) * 64);
        mfma5(Gs, ki);
    }
    #pragma unroll
    for (int nt = 0; nt < 5; ++nt) {
        int cn = nt * 32 + wn * 16 + lm;
        if (cn < 150) {
            #pragma unroll
            for (int r = 0; r < 4; ++r)
                R[(long)(gm0 + cml + r) * 600 + 150 + cn] = acc[nt][r] + dq[nt][r];
        }
    }

    // ---- Phase D: out = G0 @ WoutL^T + R3 + bout  (N=300, two passes) -----
    #pragma unroll
    for (int g = 0; g < 2; ++g) {
        float d3[5][4], bop[5];
        #pragma unroll
        for (int nt = 0; nt < 5; ++nt) {
            int cn = (g * 5 + nt) * 32 + wn * 16 + lm;
            bop[nt] = (cn < 300) ? boutv[cn] : 0.f;
            #pragma unroll
            for (int r = 0; r < 4; ++r)
                d3[nt][r] = (cn < 300) ? R[(long)(gm0 + cml + r) * 600 + 300 + cn] : 0.f;
        }
        #pragma unroll
        for (int nt = 0; nt < 5; ++nt) acc[nt] = fz;
        stageB_W(Wout, 300, g * 160, 300, 150, 0);
        for (int ki = 0; ki < 3; ++ki) {
            __syncthreads();
            stashB_r();
            __syncthreads();
            if (ki < 2) stageB_W(Wout, 300, g * 160, 300, 150, (ki + 1) * 64);
            mfma5(Gs, ki);
        }
        #pragma unroll
        for (int nt = 0; nt < 5; ++nt) {
            int cn = (g * 5 + nt) * 32 + wn * 16 + lm;
            if (cn < 300) {
                #pragma unroll
                for (int r = 0; r < 4; ++r)
                    out[(long)(gm0 + cml + r) * 300 + cn] = acc[nt][r] + d3[nt][r] + bop[nt];
            }
        }
    }
}

// ---------------------------------------------------------------------------
// fused45: one block per 32-row strip. Phase A: G1 strip = relu(A1@P1 + P1 +
// 2 b1), A1 fused from wadj+s12 (verified A1M transform); G1 kept in LDS.
// Phase C: out += G1 @ WoutR^T. G1 never touches global.
// ---------------------------------------------------------------------------
__global__ __launch_bounds__(256)
void fused45(const float* __restrict__ wadj, float* __restrict__ R,
             const float* __restrict__ b1v, const float* __restrict__ Wout,
             const float* __restrict__ smv, const float* __restrict__ s12v,
             float* __restrict__ out)
{
    __shared__ short A6[6 * 2304];
    __shared__ short Bs5[5 * 2304];
    __shared__ short Gs[3 * 2304];

    const int tid  = threadIdx.x;
    const int wave = tid >> 6, lane = tid & 63;
    const int wm = wave & 1, wn = wave >> 1;
    const int lm = lane & 15, quad = lane >> 4;
    const int srow = tid >> 3, sk = (tid & 7) * 8;
    const int nc = tid & 31, kr = tid >> 5;
    const int cml = wm * 16 + quad * 4;

    const int b  = blockIdx.x / 12;
    const int m0 = (blockIdx.x % 12) * 32;
    const int gm0 = b * Sc + m0;
    const float* Ap = wadj + (long)b * (Sc * Sc);
    const float* Pp = R    + (long)b * (Sc * 600);

    for (int i = tid; i < 3 * 2304; i += 256) Gs[i] = 0;

    // A1 strip -> A6 (verified A1M transform)
    const float sbh = smv[384];
    const float* s1p = s12v + 2L * Sc * b;
    const float s2v = s1p[2 * (m0 + srow) + 1];
    #pragma unroll
    for (int c = 0; c < 6; ++c) {
        int kb = c * 64 + sk;
        const float* ap = Ap + (long)(m0 + srow) * Sc + kb;
        float4 u = *(const float4*)ap;
        float4 w = *(const float4*)(ap + 4);
        const float* up = (const float*)&u;
        const float* wp = (const float*)&w;
        short* d = A6 + c * 2304 + srow * 72 + sk;
        #pragma unroll
        for (int j = 0; j < 4; ++j) {
            d[j]     = f2bf((up[j] + s1p[2*(kb + j)]     + s2v + sbh) * (1.0f/Ec));
            d[4 + j] = f2bf((wp[j] + s1p[2*(kb + 4 + j)] + s2v + sbh) * (1.0f/Ec));
        }
    }

    // phase-A epilogue preloads (P1 strip + b1)
    float dpre[5][4], b1pre[5];
    #pragma unroll
    for (int nt = 0; nt < 5; ++nt) {
        int cn = nt * 32 + wn * 16 + lm;
        b1pre[nt] = (cn < 150) ? b1v[cn] : 0.f;
        #pragma unroll
        for (int r = 0; r < 4; ++r)
            dpre[nt][r] = (cn < 150) ? Pp[(long)(m0 + cml + r) * 600 + 150 + cn] : 0.f;
    }

    float rbs[5][8];
    f32x4 acc[5];
    const f32x4 fz = {0.f, 0.f, 0.f, 0.f};

    auto stageB_P = [&](int k0) {                // P1 k-major (col offset 150)
        #pragma unroll
        for (int nt = 0; nt < 5; ++nt) {
            int n = nt * 32 + nc; bool nok = n < 150;
            #pragma unroll
            for (int p = 0; p < 8; ++p)
                rbs[nt][p] = nok ? Pp[(long)(k0 + kr + p * 8) * 600 + 150 + n] : 0.f;
        }
    };
    auto stashB_k = [&]() {
        #pragma unroll
        for (int nt = 0; nt < 5; ++nt)
            #pragma unroll
            for (int p = 0; p < 8; ++p)
                Bs5[nt * 2304 + nc * 72 + kr + p * 8] = f2bf(rbs[nt][p]);
    };
    auto stageB_W = [&](int nbase, int k0) {     // WoutR rows
        #pragma unroll
        for (int nt = 0; nt < 5; ++nt) {
            int nr = nbase + nt * 32 + srow; bool nok = nr < 300;
            const float* wp = Wout + (long)nr * 300 + 150;
            #pragma unroll
            for (int p = 0; p < 4; ++p) {
                int k = k0 + sk + 2 * p;
                rbs[nt][2*p]   = (nok && k     < 150) ? wp[k]     : 0.f;
                rbs[nt][2*p+1] = (nok && k + 1 < 150) ? wp[k + 1] : 0.f;
            }
        }
    };
    auto stashB_r = [&]() {
        #pragma unroll
        for (int nt = 0; nt < 5; ++nt)
            #pragma unroll
            for (int j = 0; j < 8; ++j)
                Bs5[nt * 2304 + srow * 72 + sk + j] = f2bf(rbs[nt][j]);
    };
    auto mfma5 = [&](const short* Abase, int ki) {
        const short* Af = Abase + ki * 2304 + (wm * 16 + lm) * 72;
        bf16x8 a0 = *(const bf16x8*)(Af + quad * 8);
        bf16x8 a1 = *(const bf16x8*)(Af + 32 + quad * 8);
        #pragma unroll
        for (int nt = 0; nt < 5; ++nt) {
            const short* Bf = Bs5 + nt * 2304 + (wn * 16 + lm) * 72;
            acc[nt] = __builtin_amdgcn_mfma_f32_16x16x32_bf16(
                a0, *(const bf16x8*)(Bf + quad * 8), acc[nt], 0, 0, 0);
            acc[nt] = __builtin_amdgcn_mfma_f32_16x16x32_bf16(
                a1, *(const bf16x8*)(Bf + 32 + quad * 8), acc[nt], 0, 0, 0);
        }
    };

    // ---- Phase A: G1 strip ------------------------------------------------
    #pragma unroll
    for (int nt = 0; nt < 5; ++nt) acc[nt] = fz;
    stageB_P(0);
    for (int ki = 0; ki < 6; ++ki) {
        __syncthreads();
        stashB_k();
        __syncthreads();
        if (ki < 5) stageB_P((ki + 1) * 64);
        mfma5(A6, ki);
    }
    #pragma unroll
    for (int nt = 0; nt < 5; ++nt) {
        int cn = nt * 32 + wn * 16 + lm;
        if (cn < 150) {
            #pragma unroll
            for (int r = 0; r < 4; ++r) {
                float g = fmaxf(acc[nt][r] + dpre[nt][r] + 2.f * b1pre[nt], 0.f);
                Gs[(cn >> 6) * 2304 + (cml + r) * 72 + (cn & 63)] = f2bf(g);
            }
        }
    }
    __syncthreads();

    // ---- Phase C: out += G1 @ WoutR^T  (N=300, two passes) ----------------
    #pragma unroll
    for (int g = 0; g < 2; ++g) {
        float op[5][4];
        #pragma unroll
        for (int nt = 0; nt < 5; ++nt) {
            int cn = (g * 5 + nt) * 32 + wn * 16 + lm;
            #pragma unroll
            for (int r = 0; r < 4; ++r)
                op[nt][r] = (cn < 300) ? out[(long)(gm0 + cml + r) * 300 + cn] : 0.f;
        }
        #pragma unroll
        for (int nt = 0; nt < 5; ++nt) acc[nt] = fz;
        stageB_W(g * 160, 0);
        for (int ki = 0; ki < 3; ++ki) {
            __syncthreads();
            stashB_r();
            __syncthreads();
            if (ki < 2) stageB_W(g * 160, (ki + 1) * 64);
            mfma5(Gs, ki);
        }
        #pragma unroll
        for (int nt = 0; nt < 5; ++nt) {
            int cn = (g * 5 + nt) * 32 + wn * 16 + lm;
            if (cn < 300) {
                #pragma unroll
                for (int r = 0; r < 4; ++r)
                    out[(long)(gm0 + cml + r) * 300 + cn] = acc[nt][r] + op[nt][r];
            }
        }
    }
}

extern "C" void kernel_launch(void* const* d_in, const int* in_sizes, int n_in,
                              void* d_out, int out_size, void* d_ws, size_t ws_size,
                              hipStream_t stream) {
    const float* adj  = (const float*)d_in[0];
    const float* X    = (const float*)d_in[1];
    const float* W0   = (const float*)d_in[2];
    const float* b0   = (const float*)d_in[3];
    const float* W1   = (const float*)d_in[4];
    const float* b1   = (const float*)d_in[5];
    const float* Wh   = (const float*)d_in[6];
    const float* bh   = (const float*)d_in[7];
    const float* Wout = (const float*)d_in[8];
    const float* bout = (const float*)d_in[9];
    float* out = (float*)d_out;

    // workspace layout (floats) — unchanged; Gbuf now unused
    float* ws   = (float*)d_ws;
    float* sm   = ws;                          // 512
    float* A0   = sm + 512;                    // 1536 x 384
    float* wadj = A0 + Bc * Sc * Sc;           // 1536 x 384
    float* R    = wadj + Bc * Sc * Sc;         // 1536 x 600: [P0 | P1 | X@Wout^T]
    float* Gbuf = R + (long)Bc * Sc * 600;     // (unused)
    float* s12  = Gbuf + (long)Bc * Sc * Dc;   // 1536 x 2 interleaved

    // D1: gemm3 + sm + adj reduction  (912 + 1 + 9216 blocks)
    fused1<<<912 + 1 + (Bc*Sc*Sc)/64, 256, 0, stream>>>(
        adj, X, W0, W1, Wout, Wh, bh, sm, A0, wadj, R);

    // D2: G0 strip + s12 + P1 + out(G0 part)  (48 blocks)
    fused23<<<48, 256, 0, stream>>>(
        A0, R, W1, Wout, b0, bout, sm, s12, out);

    // D3: G1 strip + out += G1@WoutR^T  (48 blocks)
    fused45<<<48, 256, 0, stream>>>(
        wadj, R, b1, Wout, sm, s12, out);
}

// Round 7
// 225.424 us; speedup vs baseline: 1.1309x; 1.1309x over previous
//
#include <hip/hip_runtime.h>

// Problem constants
constexpr int Bc  = 4;
constexpr int Sc  = 384;
constexpr int Dc  = 300;
constexpr int Ec  = 50;
constexpr int HDc = 150;          // D / L
constexpr int WHC = 350;          // Wh row length
constexpr int MT  = Bc * Sc;      // 1536

typedef __attribute__((ext_vector_type(8))) short bf16x8;
typedef __attribute__((ext_vector_type(4))) float f32x4;

__device__ __forceinline__ short f2bf(float x) {
    union { float f; unsigned u; } v; v.f = x;
    unsigned r = (v.u + 0x7FFFu + ((v.u >> 16) & 1u)) >> 16;
    return (short)r;
}

// ---------------------------------------------------------------------------
// s12 unit: wave per row. s12[2g] = G0[g]·w1cs, s12[2g+1] = G0[g]·w2cs
// ---------------------------------------------------------------------------
__device__ __forceinline__ void s12_unit(const float* __restrict__ G,
                                         const float* __restrict__ sm,
                                         float* __restrict__ s12, int unit)
{
    int wave = threadIdx.x >> 6, lane = threadIdx.x & 63;
    int g = unit * 4 + wave;
    const float* gp = G + (long)g * Dc;
    float a = 0.f, c = 0.f;
    #pragma unroll
    for (int h0 = 0; h0 < HDc; h0 += 64) {
        int h = h0 + lane;
        if (h < HDc) { float v = gp[h]; a += v * sm[64 + h]; c += v * sm[224 + h]; }
    }
    #pragma unroll
    for (int off = 32; off; off >>= 1) {
        a += __shfl_down(a, off);
        c += __shfl_down(c, off);
    }
    if (lane == 0) { s12[2*g] = a; s12[2*g + 1] = c; }
}

// ---------------------------------------------------------------------------
// bf16 MFMA GEMM body, 256 thr = 4 waves, 32x32 C tile, BK=64 (two
// mfma_f32_16x16x32_bf16 per wave per iter), fp32->bf16 fused into LDS
// staging (scalar f2bf — NOT inline-asm cvt_pk, per m240: asm in the stash
// path defeats compiler scheduling, measured ~9us regression r3/r4),
// single-buffer register prefetch (one-iter distance covers the ~200cy L2
// latency; depth-2 measured neutral-to-harmful). LDS row stride 72 shorts.
// PRE=1 (standalone 1-block/CU launchers only): hoist epilogue D/bias loads
// above the K-loop so their latency hides under the GEMM instead of sitting
// exposed after the last MFMA. fused1 uses PRE=0 = round-2-exact body.
// BSRC 0: B k-major (ld ldb, batched sB). 1: B row-major N x K (ld ldb).
// 2: B = concat [W0 | W1[:,0:300] | Wout] row-major, K=300.
// A1M: A element = (wadj + s1[k] + s2[m] + sbh)/E from s12/sm
// ---------------------------------------------------------------------------
template<int BSRC, int A1M, int HASD, int HASB, int RELU, int PRE>
__device__ __forceinline__ void mgemm_body(
    short* As, short* Bs, int bx, int by, int b,
    const float* __restrict__ A, int lda, long sA,
    const float* __restrict__ Bw, int ldb, long sB,
    const float* __restrict__ W1a, const float* __restrict__ WoutP,
    const float* __restrict__ Dm, int ldd, long sD,
    const float* __restrict__ bias, float bscale,
    const float* __restrict__ s12, const float* __restrict__ sm,
    float* __restrict__ C, int ldc, long sC,
    int M, int N, int K)
{
    const float* Ap = A + (long)b * sA;
    const float* Bp = Bw + (long)b * sB;
    const float* Dp = Dm + (long)b * sD;
    float* Cp = C + (long)b * sC;

    const int tid  = threadIdx.x;
    const int wave = tid >> 6, lane = tid & 63;
    const int wm = wave & 1, wn = wave >> 1;
    const int lm = lane & 15, quad = lane >> 4;
    const int m0 = by * 32, n0 = bx * 32;

    const int srow = tid >> 3;           // 0..31 (A rows / B n-rows)
    const int sk   = (tid & 7) * 8;      // 0,8,..,56
    const int nc   = tid & 31;           // BSRC0 n
    const int kr   = tid >> 5;           // BSRC0 k base 0..7

    float sbh = 0.f; const float* s1p = nullptr; float s2v = 0.f;
    if constexpr (A1M) {
        sbh = sm[384];
        s1p = s12 + 2L * Sc * b;
        s2v = s1p[2 * (m0 + srow) + 1];
    }

    const int cn = n0 + wn * 16 + lm;
    // PRE=1: epilogue operand preloads issue here and retire under the K-loop
    float bpre = 0.f;
    float dpre[4] = {0.f, 0.f, 0.f, 0.f};
    if constexpr (PRE) {
        if constexpr (HASB) { if (cn < N) bpre = bias[cn]; }
        if constexpr (HASD) {
            #pragma unroll
            for (int r = 0; r < 4; ++r) {
                int cm = m0 + wm * 16 + quad * 4 + r;
                if (cn < N && cm < M) dpre[r] = Dp[(long)cm * ldd + cn];
            }
        }
    }

    float ra[8], rb[8];

    auto stageA = [&](int k0) {
        int am = m0 + srow;
        int kb = k0 + sk;
        if constexpr (A1M) {             // K=384 exact, no masks
            float4 u = *(const float4*)(Ap + (long)am * lda + kb);
            float4 w = *(const float4*)(Ap + (long)am * lda + kb + 4);
            const float* up = (const float*)&u;
            const float* wp = (const float*)&w;
            #pragma unroll
            for (int j = 0; j < 4; ++j) {
                ra[j]     = (up[j] + s1p[2*(kb + j)]     + s2v + sbh) * (1.0f/Ec);
                ra[4 + j] = (wp[j] + s1p[2*(kb + 4 + j)] + s2v + sbh) * (1.0f/Ec);
            }
        } else {
            if (kb + 7 < K) {
                float4 u = *(const float4*)(Ap + (long)am * lda + kb);
                float4 w = *(const float4*)(Ap + (long)am * lda + kb + 4);
                ra[0]=u.x; ra[1]=u.y; ra[2]=u.z; ra[3]=u.w;
                ra[4]=w.x; ra[5]=w.y; ra[6]=w.z; ra[7]=w.w;
            } else {
                #pragma unroll
                for (int j = 0; j < 8; ++j) {
                    int k = kb + j;
                    ra[j] = (k < K) ? Ap[(long)am * lda + k] : 0.f;
                }
            }
        }
    };

    auto stageB = [&](int k0) {
        if constexpr (BSRC == 0) {       // k-major, K=384 exact here
            int n = n0 + nc;
            bool nok = n < N;
            #pragma unroll
            for (int p = 0; p < 8; ++p) {
                int k = k0 + kr + p * 8;
                rb[p] = nok ? Bp[(long)k * ldb + n] : 0.f;
            }
        } else {
            int nr = n0 + srow;
            bool nok = nr < N;
            const float* wp = Bp; int ld = ldb; int nn = nr;
            if constexpr (BSRC == 2) {
                if (nr < 150)      { wp = Bp;    ld = 300; nn = nr; }
                else if (nr < 300) { wp = W1a;   ld = 450; nn = nr - 150; }
                else               { wp = WoutP; ld = 300; nn = nr - 300; }
            }
            #pragma unroll
            for (int p = 0; p < 4; ++p) {
                int k = k0 + sk + 2 * p;
                if (nok && k + 1 < K) {
                    float2 v = *(const float2*)(wp + (long)nn * ld + k);
                    rb[2*p] = v.x; rb[2*p + 1] = v.y;
                } else {
                    rb[2*p]     = (nok && k < K)     ? wp[(long)nn * ld + k]     : 0.f;
                    rb[2*p + 1] = (nok && k + 1 < K) ? wp[(long)nn * ld + k + 1] : 0.f;
                }
            }
        }
    };

    auto stash = [&]() {
        #pragma unroll
        for (int j = 0; j < 8; ++j) As[srow * 72 + sk + j] = f2bf(ra[j]);
        if constexpr (BSRC == 0) {
            #pragma unroll
            for (int p = 0; p < 8; ++p) Bs[nc * 72 + kr + p * 8] = f2bf(rb[p]);
        } else {
            #pragma unroll
            for (int j = 0; j < 8; ++j) Bs[srow * 72 + sk + j] = f2bf(rb[j]);
        }
    };

    f32x4 acc = {0.f, 0.f, 0.f, 0.f};

    stageA(0); stageB(0);
    for (int k0 = 0; k0 < K; k0 += 64) {
        __syncthreads();
        stash();
        __syncthreads();
        if (k0 + 64 < K) { stageA(k0 + 64); stageB(k0 + 64); }
        {
            bf16x8 a0 = *(const bf16x8*)(As + (wm*16 + lm) * 72 + quad * 8);
            bf16x8 b0 = *(const bf16x8*)(Bs + (wn*16 + lm) * 72 + quad * 8);
            acc = __builtin_amdgcn_mfma_f32_16x16x32_bf16(a0, b0, acc, 0, 0, 0);
            bf16x8 a1 = *(const bf16x8*)(As + (wm*16 + lm) * 72 + 32 + quad * 8);
            bf16x8 b1 = *(const bf16x8*)(Bs + (wn*16 + lm) * 72 + 32 + quad * 8);
            acc = __builtin_amdgcn_mfma_f32_16x16x32_bf16(a1, b1, acc, 0, 0, 0);
        }
    }

    if (cn < N) {
        #pragma unroll
        for (int r = 0; r < 4; ++r) {
            int cm = m0 + wm * 16 + quad * 4 + r;
            if (cm < M) {
                float v = acc[r];
                if constexpr (HASD) v += PRE ? dpre[r] : Dp[(long)cm * ldd + cn];
                if constexpr (HASB) v += bscale * (PRE ? bpre : bias[cn]);
                if constexpr (RELU) v = fmaxf(v, 0.f);
                Cp[(long)cm * ldc + cn] = v;
            }
        }
    }
}

// standalone GEMM launcher (D2, D4, D5) — PRE=1 (1 block/CU, VGPR free)
template<int BSRC, int A1M, int HASD, int HASB, int RELU>
__global__ __launch_bounds__(256)
void mgemm(const float* __restrict__ A, int lda, long sA,
           const float* __restrict__ Bw, int ldb, long sB,
           const float* __restrict__ W1a, const float* __restrict__ WoutP,
           const float* __restrict__ Dm, int ldd, long sD,
           const float* __restrict__ bias, float bscale,
           const float* __restrict__ s12, const float* __restrict__ sm,
           float* __restrict__ C, int ldc, long sC,
           int M, int N, int K)
{
    __shared__ short As[32 * 72];
    __shared__ short Bs[32 * 72];
    mgemm_body<BSRC,A1M,HASD,HASB,RELU,1>(As, Bs,
        blockIdx.x, blockIdx.y, blockIdx.z,
        A, lda, sA, Bw, ldb, sB, W1a, WoutP, Dm, ldd, sD,
        bias, bscale, s12, sm, C, ldc, sC, M, N, K);
}

// ---------------------------------------------------------------------------
// D1: gemm3 (912 blocks) + sm prep (1 block) + adj reduction (9216 blocks).
// Reduce blocks compute wec (Wh col-sums, L2-resident) UNDER the in-flight
// adj loads -> no separate prep dependency. LDS union, 13.3 KB.
// PRE=0 gemm body: round-2-exact, low VGPR, so reduce blocks keep 8/CU
// (the reduce is the only pipe-bound phase; occupancy is the HBM lever).
// ---------------------------------------------------------------------------
__global__ __launch_bounds__(256)
void fused1(const float* __restrict__ adj, const float* __restrict__ X,
            const float* __restrict__ W0, const float* __restrict__ W1,
            const float* __restrict__ Wout, const float* __restrict__ Wh,
            const float* __restrict__ bh,
            float* __restrict__ sm, float* __restrict__ A0,
            float* __restrict__ wadj, float* __restrict__ R)
{
    __shared__ float lds[64 * 51 + 64];      // 13312 B union
    const int bx = blockIdx.x, t = threadIdx.x;

    if (bx < 912) {
        // R = X @ [W0 | W1a | Wout]^T  (M=1536, N=600, K=300)
        short* As = (short*)lds;
        short* Bs = As + 32 * 72;
        mgemm_body<2,0,0,0,0,0>(As, Bs, bx % 19, bx / 19, 0,
            X, Dc, 0, W0, 300, 0, W1, Wout,
            nullptr, 0, 0, nullptr, 0.f, nullptr, nullptr,
            R, 600, 0, MT, 600, Dc);
    } else if (bx == 912) {
        // sm: [0..49] we, [64..213] w1, [224..373] w2, [384] sum(bh)
        for (int u = t; u < 512; u += 256) {
            if (u < Ec) {
                float s = 0.f;
                for (int e = 0; e < Ec; ++e) s += Wh[e*WHC + u];
                sm[u] = s;
            } else if (u >= 64 && u < 64 + HDc) {
                int h = u - 64; float s = 0.f;
                for (int e = 0; e < Ec; ++e) s += Wh[e*WHC + Ec + h];
                sm[u] = s;
            } else if (u >= 224 && u < 224 + HDc) {
                int h = u - 224; float s = 0.f;
                for (int e = 0; e < Ec; ++e) s += Wh[e*WHC + Ec + HDc + h];
                sm[u] = s;
            } else if (u == 384) {
                float s = 0.f;
                for (int e = 0; e < Ec; ++e) s += bh[e];
                sm[u] = s;
            }
        }
    } else {
        // 64-row adj tile: A0[g] = (sum_e adj[g,:])/E ; wadj[g] = sum adj*we
        const int unit = bx - 913;
        float* tile = lds;
        float* wec  = lds + 64 * 51;

        long base = (long)unit * 3200;       // 64 rows * 50 floats
        const float4* p4 = (const float4*)(adj + base);
        float4 v0 = p4[t];
        float4 v1 = p4[t + 256];
        float4 v2 = p4[t + 512];
        float4 v3 = {0.f, 0.f, 0.f, 0.f};
        if (t < 32) v3 = p4[t + 768];

        // Wh col-sums hide under the HBM loads above (Wh is L2-resident)
        if (t < Ec) {
            float s = 0.f;
            for (int e = 0; e < Ec; ++e) s += Wh[e * WHC + t];
            wec[t] = s;
        }

        auto scat = [&](int i, const float4& v) {
            const float* vp = (const float*)&v;
            #pragma unroll
            for (int j = 0; j < 4; ++j) {
                int e = 4 * i + j;
                tile[(e / 50) * 51 + (e % 50)] = vp[j];
            }
        };
        scat(t, v0);
        scat(t + 256, v1);
        scat(t + 512, v2);
        if (t < 32) scat(t + 768, v3);
        __syncthreads();

        int r = t >> 2, q = t & 3;
        int h0 = q * 13, h1 = (q == 3) ? 50 : h0 + 13;
        const float* row = tile + r * 51;
        float s = 0.f, w = 0.f;
        for (int i = h0; i < h1; ++i) { float v = row[i]; s += v; w += v * wec[i]; }
        s += __shfl_xor(s, 1); w += __shfl_xor(w, 1);
        s += __shfl_xor(s, 2); w += __shfl_xor(w, 2);
        if (q == 0) {
            int g = unit * 64 + r;
            A0[g]   = s * (1.0f / Ec);
            wadj[g] = w;
        }
    }
}

// ---------------------------------------------------------------------------
// D3: gemm8a (480) + gemm6 (240) + s12 (384) fused — all independent, all
// read G0. out = G0@WoutL^T + R3 + bout ; P1 = Q1 + G0@W1b^T ; s12 rows.
// ---------------------------------------------------------------------------
__global__ __launch_bounds__(256)
void fused3(const float* __restrict__ Gbuf, const float* __restrict__ sm,
            float* __restrict__ s12, const float* __restrict__ W1,
            float* __restrict__ R, const float* __restrict__ Wout,
            const float* __restrict__ bout, float* __restrict__ out)
{
    __shared__ short As[32 * 72];
    __shared__ short Bs[32 * 72];
    const int bx = blockIdx.x;

    if (bx < 480) {
        // out = G0 @ WoutL^T + R3 + bout  (M=1536, N=300, K=150)
        mgemm_body<1,0,1,1,0,1>(As, Bs, bx % 10, bx / 10, 0,
            Gbuf, Dc, 0, Wout, Dc, 0, nullptr, nullptr,
            R + 2 * HDc, 600, 0, bout, 1.0f, nullptr, nullptr,
            out, Dc, 0, MT, Dc, HDc);
    } else if (bx < 480 + 240) {
        // P1 = Q1 + G0 @ W1b^T  (M=1536, N=150, K=150; in-place R[:,150:300])
        int v = bx - 480;
        mgemm_body<1,0,1,0,0,1>(As, Bs, v % 5, v / 5, 0,
            Gbuf, Dc, 0, W1 + Dc, Dc + HDc, 0, nullptr, nullptr,
            R + HDc, 600, 0, nullptr, 0.f, nullptr, nullptr,
            R + HDc, 600, 0, MT, HDc, HDc);
    } else {
        s12_unit(Gbuf, sm, s12, bx - 720);
    }
}

extern "C" void kernel_launch(void* const* d_in, const int* in_sizes, int n_in,
                              void* d_out, int out_size, void* d_ws, size_t ws_size,
                              hipStream_t stream) {
    const float* adj  = (const float*)d_in[0];
    const float* X    = (const float*)d_in[1];
    const float* W0   = (const float*)d_in[2];
    const float* b0   = (const float*)d_in[3];
    const float* W1   = (const float*)d_in[4];
    const float* b1   = (const float*)d_in[5];
    const float* Wh   = (const float*)d_in[6];
    const float* bh   = (const float*)d_in[7];
    const float* Wout = (const float*)d_in[8];
    const float* bout = (const float*)d_in[9];
    float* out = (float*)d_out;

    // workspace layout (floats)
    float* ws   = (float*)d_ws;
    float* sm   = ws;                          // 512
    float* A0   = sm + 512;                    // 1536 x 384
    float* wadj = A0 + Bc * Sc * Sc;           // 1536 x 384
    float* R    = wadj + Bc * Sc * Sc;         // 1536 x 600: [P0 | P1 | X@Wout^T]
    float* Gbuf = R + (long)Bc * Sc * 600;     // 1536 x 300: [G0 | G1]
    float* s12  = Gbuf + (long)Bc * Sc * Dc;   // 1536 x 2 interleaved

    const long AS = (long)Sc * Sc;             // adj batch stride
    const long RS = (long)Sc * 600;            // R batch stride (rows)
    const long GS = (long)Sc * Dc;             // Gbuf batch stride

    // D1: gemm3 + sm + adj reduction  (912 + 1 + 9216 blocks)
    fused1<<<912 + 1 + (Bc*Sc*Sc)/64, 256, 0, stream>>>(
        adj, X, W0, W1, Wout, Wh, bh, sm, A0, wadj, R);

    // D2: G0 = relu(A0 @ P0 + P0 + 2*b0)  (batched; M=384, N=150, K=384)
    mgemm<0,0,1,1,1><<<dim3(5, 12, Bc), 256, 0, stream>>>(
        A0, Sc, AS, R, 600, RS, nullptr, nullptr,
        R, 600, RS, b0, 2.0f, nullptr, nullptr,
        Gbuf, Dc, GS, Sc, HDc, Sc);

    // D3: gemm8a + gemm6 + s12  (480 + 240 + 384 blocks)
    fused3<<<480 + 240 + 384, 256, 0, stream>>>(
        Gbuf, sm, s12, W1, R, Wout, bout, out);

    // D4: G1 = relu(A1 @ P1 + P1 + 2*b1); A1 fused from wadj+s12 (batched)
    mgemm<0,1,1,1,1><<<dim3(5, 12, Bc), 256, 0, stream>>>(
        wadj, Sc, AS, R + HDc, 600, RS, nullptr, nullptr,
        R + HDc, 600, RS, b1, 2.0f, s12, sm,
        Gbuf + HDc, Dc, GS, Sc, HDc, Sc);

    // D5: out += G1 @ WoutR^T  (M=1536, N=300, K=150)
    mgemm<1,0,1,0,0><<<dim3(10, 48, 1), 256, 0, stream>>>(
        Gbuf + HDc, Dc, 0, Wout + HDc, Dc, 0, nullptr, nullptr,
        out, Dc, 0, nullptr, 0.f, nullptr, nullptr,
        out, Dc, 0, MT, Dc, HDc);
}